// Round 5
// baseline (1353.640 us; speedup 1.0000x reference)
//
#include <hip/hip_runtime.h>

#define P_N    20000
#define D_N    10000
#define R_N    64
#define EPER_N 16384
#define EDD_N  (R_N*EPER_N)
#define EPP_N  640000
#define EDP_N  160000
#define NE_N   48
#define PD_N   16
#define IN1_N  64   // NE+PD
#define NH1_N  32
#define NH2_N  16
#define GH1_N  32
#define GH2_N  16

static __device__ __forceinline__ int gtid() { return blockIdx.x * blockDim.x + threadIdx.x; }

__global__ void k_scatter_ones(const int* __restrict__ dst, int E, float* __restrict__ cnt) {
    int i = gtid();
    if (i < E) atomicAdd(&cnt[dst[i]], 1.0f);
}

__global__ void k_dinv(const float* __restrict__ deg, float* __restrict__ dinv, int n) {
    int i = gtid();
    if (i < n) dinv[i] = 1.0f / sqrtf(deg[i] + 1.0f);
}

// C[M,N] = A[M,K] @ W[K,N]   (small N; thread per output element)
template<int K, int N>
__global__ void k_matmul(const float* __restrict__ A, const float* __restrict__ W,
                         float* __restrict__ C, int M) {
    int id = gtid();
    if (id >= M * N) return;
    int m = id / N, n = id % N;
    const float* a = A + (size_t)m * K;
    float acc = 0.f;
#pragma unroll
    for (int k = 0; k < K; ++k) acc = fmaf(a[k], W[k * N + n], acc);
    C[id] = acc;
}

// out[dst] += h[src] * dinv[src] * dinv[dst]   (GCN message scatter)
template<int N>
__global__ void k_gcn_scatter(const float* __restrict__ h, const float* __restrict__ dinv,
                              const int* __restrict__ src, const int* __restrict__ dst,
                              int E, float* __restrict__ out) {
    int id = gtid();
    if (id >= E * N) return;
    int e = id / N, c = id % N;
    int s = src[e], d = dst[e];
    atomicAdd(&out[d * N + c], h[s * N + c] * dinv[s] * dinv[d]);
}

// agg = agg + h*dinv^2 + b  (+optional relu), in place
template<int N>
__global__ void k_gcn_finish(float* __restrict__ agg, const float* __restrict__ h,
                             const float* __restrict__ dinv, const float* __restrict__ b,
                             int M, int relu) {
    int id = gtid();
    if (id >= M * N) return;
    int m = id / N, c = id % N;
    float di = dinv[m];
    float v = agg[id] + h[id] * di * di + b[c];
    agg[id] = relu ? fmaxf(v, 0.f) : v;
}

// prot->drug mean aggregation inputs (sum + count)
__global__ void k_dp_scatter(const float* __restrict__ hp, const int* __restrict__ src,
                             const int* __restrict__ dst, float* __restrict__ sum,
                             float* __restrict__ cnt) {
    int id = gtid();
    if (id >= EDP_N * PD_N) return;
    int e = id / PD_N, c = id % PD_N;
    int s = src[e], t = dst[e] - P_N;
    atomicAdd(&sum[t * PD_N + c], hp[s * PD_N + c]);
    if (c == 0) atomicAdd(&cnt[t], 1.0f);
}

// xcat[:,48:64] = (dpsum/max(cnt,1)) @ hgcn_w
__global__ void k_hd(const float* __restrict__ sum, const float* __restrict__ cnt,
                     const float* __restrict__ w, float* __restrict__ xcat) {
    int id = gtid();
    if (id >= D_N * PD_N) return;
    int d = id / PD_N, o = id % PD_N;
    float inv = 1.0f / fmaxf(cnt[d], 1.0f);
    float acc = 0.f;
#pragma unroll
    for (int k = 0; k < PD_N; ++k) acc = fmaf(sum[d * PD_N + k] * inv, w[k * PD_N + o], acc);
    xcat[d * IN1_N + NE_N + o] = acc;
}

// xcat[:,0:48] = (x_drug @ embed) / d_norm ; LDS-tiled, 16 rows/block, K chunks of 64
#define EMB_BM 16
__global__ __launch_bounds__(256) void k_embed(const float* __restrict__ xd,
                                               const float* __restrict__ emb,
                                               const float* __restrict__ dnorm,
                                               float* __restrict__ xcat) {
    __shared__ float es[64][48];
    __shared__ float xs[EMB_BM][65];  // +1 pad: avoid same-bank across rows
    int tid = threadIdx.x;
    int row0 = blockIdx.x * EMB_BM;
    int r = tid / 16;      // 0..15 local row
    int cg = tid % 16;     // col group, 3 cols each
    float acc0 = 0.f, acc1 = 0.f, acc2 = 0.f;
    for (int k0 = 0; k0 < 2048; k0 += 64) {
        __syncthreads();
        for (int i = tid; i < 64 * 48; i += 256) es[i / 48][i % 48] = emb[(size_t)(k0 + i / 48) * 48 + i % 48];
        for (int i = tid; i < EMB_BM * 64; i += 256) {
            int rr = i / 64, kk = i % 64;
            int grow = row0 + rr;
            xs[rr][kk] = (grow < D_N) ? xd[(size_t)grow * 2048 + k0 + kk] : 0.f;
        }
        __syncthreads();
#pragma unroll
        for (int k = 0; k < 64; ++k) {
            float xv = xs[r][k];
            acc0 = fmaf(xv, es[k][cg * 3 + 0], acc0);
            acc1 = fmaf(xv, es[k][cg * 3 + 1], acc1);
            acc2 = fmaf(xv, es[k][cg * 3 + 2], acc2);
        }
    }
    int grow = row0 + r;
    if (grow < D_N) {
        float inv = 1.0f / dnorm[grow];
        xcat[grow * IN1_N + cg * 3 + 0] = acc0 * inv;
        xcat[grow * IN1_N + cg * 3 + 1] = acc1 * inv;
        xcat[grow * IN1_N + cg * 3 + 2] = acc2 * inv;
    }
}

// W[r] = sum_b att[r,b] * basis[b]   (basis-decomposed relation weights)
__global__ void k_rgcn_w(const float* __restrict__ att, const float* __restrict__ basis,
                         float* __restrict__ W, int IO) {
    int id = gtid();
    if (id >= R_N * IO) return;
    int r = id / IO, io = id % IO;
    float acc = 0.f;
#pragma unroll
    for (int b = 0; b < 32; ++b) acc = fmaf(att[r * 32 + b], basis[b * IO + io], acc);
    W[id] = acc;
}

// per-edge msg = x[src] @ W[rel], atomically accumulated at dst.
// 256 threads; CPT=4 cols/thread; 2 edges/thread; W[rel] staged in LDS.
template<int IN, int OUT>
__global__ __launch_bounds__(256) void k_rgcn_edges(const float* __restrict__ x,
                                                    const int* __restrict__ src,
                                                    const int* __restrict__ dst,
                                                    const float* __restrict__ Wall,
                                                    float* __restrict__ out) {
    constexpr int CPT = 4;
    constexpr int GP  = OUT / CPT;    // lanes per edge
    constexpr int EPI = 256 / GP;     // edges per pass
    constexpr int EB  = 2 * EPI;      // edges per block
    __shared__ float ws[IN * OUT];
    int tid = threadIdx.x;
    int e0 = blockIdx.x * EB;
    int rel = e0 >> 14;               // /EPER (16384); EB divides EPER
    for (int i = tid; i < IN * OUT; i += 256) ws[i] = Wall[rel * IN * OUT + i];
    __syncthreads();
    int c0 = (tid % GP) * CPT;
    int el = tid / GP;
    int ea = e0 + el, eb = e0 + EPI + el;
    int sa = src[ea], da = dst[ea];
    int sb = src[eb], db = dst[eb];
    const float4* xa = (const float4*)(x + (size_t)sa * IN);
    const float4* xb = (const float4*)(x + (size_t)sb * IN);
    float acca[4] = {0.f, 0.f, 0.f, 0.f};
    float accb[4] = {0.f, 0.f, 0.f, 0.f};
#pragma unroll
    for (int k4 = 0; k4 < IN / 4; ++k4) {
        float4 va = xa[k4], vb = xb[k4];
#pragma unroll
        for (int kk = 0; kk < 4; ++kk) {
            int k = k4 * 4 + kk;
            float4 w = *(const float4*)&ws[k * OUT + c0];
            float fa = kk == 0 ? va.x : kk == 1 ? va.y : kk == 2 ? va.z : va.w;
            float fb = kk == 0 ? vb.x : kk == 1 ? vb.y : kk == 2 ? vb.z : vb.w;
            acca[0] = fmaf(fa, w.x, acca[0]); acca[1] = fmaf(fa, w.y, acca[1]);
            acca[2] = fmaf(fa, w.z, acca[2]); acca[3] = fmaf(fa, w.w, acca[3]);
            accb[0] = fmaf(fb, w.x, accb[0]); accb[1] = fmaf(fb, w.y, accb[1]);
            accb[2] = fmaf(fb, w.z, accb[2]); accb[3] = fmaf(fb, w.w, accb[3]);
        }
    }
#pragma unroll
    for (int j = 0; j < 4; ++j) {
        atomicAdd(&out[(size_t)da * OUT + c0 + j], acca[j]);
        atomicAdd(&out[(size_t)db * OUT + c0 + j], accb[j]);
    }
}

// out = sum/max(cnt,1) + x @ root  (+optional relu)
template<int IN, int OUT>
__global__ void k_rgcn_finish(const float* __restrict__ sum, const float* __restrict__ cnt,
                              const float* __restrict__ x, const float* __restrict__ root,
                              float* __restrict__ out, int relu) {
    int id = gtid();
    if (id >= D_N * OUT) return;
    int m = id / OUT, o = id % OUT;
    float acc = sum[id] / fmaxf(cnt[m], 1.0f);
#pragma unroll
    for (int k = 0; k < IN; ++k) acc = fmaf(x[m * IN + k], root[k * OUT + o], acc);
    out[id] = relu ? fmaxf(acc, 0.f) : acc;
}

extern "C" void kernel_launch(void* const* d_in, const int* in_sizes, int n_in,
                              void* d_out, int out_size, void* d_ws, size_t ws_size,
                              hipStream_t stream) {
    const float* x_drug   = (const float*)d_in[0];
    const int*   dd_ei    = (const int*)d_in[1];
    const float* d_norm   = (const float*)d_in[4];
    const float* x_prot   = (const float*)d_in[5];
    const int*   pp_ei    = (const int*)d_in[6];
    const int*   dp_ei    = (const int*)d_in[7];
    const float* gcn_w1   = (const float*)d_in[9];
    const float* gcn_b1   = (const float*)d_in[10];
    const float* gcn_w2   = (const float*)d_in[11];
    const float* gcn_b2   = (const float*)d_in[12];
    const float* embed    = (const float*)d_in[13];
    const float* hgcn_w   = (const float*)d_in[14];
    const float* r1_basis = (const float*)d_in[15];
    const float* r1_att   = (const float*)d_in[16];
    const float* r1_root  = (const float*)d_in[17];
    const float* r2_basis = (const float*)d_in[18];
    const float* r2_att   = (const float*)d_in[19];
    const float* r2_root  = (const float*)d_in[20];
    float* out = (float*)d_out;

    float* ws = (float*)d_ws;
    size_t off = 0;
    auto alloc = [&](size_t n) { float* p = ws + off; off += (n + 63) & ~(size_t)63; return p; };
    // ---- zeroed region (accumulators) ----
    float* deg   = alloc(P_N);
    float* agg1  = alloc(P_N * GH1_N);
    float* agg2  = alloc(P_N * GH2_N);
    float* dpsum = alloc(D_N * PD_N);
    float* dpcnt = alloc(D_N);
    float* ddcnt = alloc(D_N);
    float* rsum1 = alloc(D_N * NH1_N);
    float* rsum2 = alloc(D_N * NH2_N);
    size_t zlen = off;
    // ---- scratch (written before read) ----
    float* dinv = alloc(P_N);
    float* h1   = alloc(P_N * GH1_N);
    float* h2   = alloc(P_N * GH2_N);
    float* xcat = alloc(D_N * IN1_N);
    float* W1   = alloc(R_N * IN1_N * NH1_N);
    float* W2   = alloc(R_N * NH1_N * NH2_N);
    float* h1d  = alloc(D_N * NH1_N);

    hipMemsetAsync(d_ws, 0, zlen * sizeof(float), stream);

    auto g = [](int n) { return (n + 255) / 256; };
    const int *pp_src = pp_ei, *pp_dst = pp_ei + EPP_N;
    const int *dd_src = dd_ei, *dd_dst = dd_ei + EDD_N;
    const int *dp_src = dp_ei, *dp_dst = dp_ei + EDP_N;

    // PPEncoder layer 1
    k_scatter_ones<<<g(EPP_N), 256, 0, stream>>>(pp_dst, EPP_N, deg);
    k_dinv<<<g(P_N), 256, 0, stream>>>(deg, dinv, P_N);
    k_matmul<128, GH1_N><<<g(P_N * GH1_N), 256, 0, stream>>>(x_prot, gcn_w1, h1, P_N);
    k_gcn_scatter<GH1_N><<<g(EPP_N * GH1_N), 256, 0, stream>>>(h1, dinv, pp_src, pp_dst, EPP_N, agg1);
    k_gcn_finish<GH1_N><<<g(P_N * GH1_N), 256, 0, stream>>>(agg1, h1, dinv, gcn_b1, P_N, 1);
    // PPEncoder layer 2
    k_matmul<GH1_N, GH2_N><<<g(P_N * GH2_N), 256, 0, stream>>>(agg1, gcn_w2, h2, P_N);
    k_gcn_scatter<GH2_N><<<g(EPP_N * GH2_N), 256, 0, stream>>>(h2, dinv, pp_src, pp_dst, EPP_N, agg2);
    k_gcn_finish<GH2_N><<<g(P_N * GH2_N), 256, 0, stream>>>(agg2, h2, dinv, gcn_b2, P_N, 0);
    // hierarchy conv: prot->drug mean + project (writes xcat[:,48:64])
    k_dp_scatter<<<g(EDP_N * PD_N), 256, 0, stream>>>(agg2, dp_src, dp_dst, dpsum, dpcnt);
    k_hd<<<g(D_N * PD_N), 256, 0, stream>>>(dpsum, dpcnt, hgcn_w, xcat);
    // drug embedding (writes xcat[:,0:48])
    k_embed<<<(D_N + EMB_BM - 1) / EMB_BM, 256, 0, stream>>>(x_drug, embed, d_norm, xcat);
    // RGCN relation weights
    k_rgcn_w<<<g(R_N * IN1_N * NH1_N), 256, 0, stream>>>(r1_att, r1_basis, W1, IN1_N * NH1_N);
    k_rgcn_w<<<g(R_N * NH1_N * NH2_N), 256, 0, stream>>>(r2_att, r2_basis, W2, NH1_N * NH2_N);
    // dd in-degree counts (shared by both RGCN layers)
    k_scatter_ones<<<g(EDD_N), 256, 0, stream>>>(dd_dst, EDD_N, ddcnt);
    // RGCN layer 1 (relu)
    k_rgcn_edges<IN1_N, NH1_N><<<EDD_N / 64, 256, 0, stream>>>(xcat, dd_src, dd_dst, W1, rsum1);
    k_rgcn_finish<IN1_N, NH1_N><<<g(D_N * NH1_N), 256, 0, stream>>>(rsum1, ddcnt, xcat, r1_root, h1d, 1);
    // RGCN layer 2 (final output)
    k_rgcn_edges<NH1_N, NH2_N><<<EDD_N / 128, 256, 0, stream>>>(h1d, dd_src, dd_dst, W2, rsum2);
    k_rgcn_finish<NH1_N, NH2_N><<<g(D_N * NH2_N), 256, 0, stream>>>(rsum2, ddcnt, h1d, r2_root, out, 0);
}

// Round 8
// 947.357 us; speedup vs baseline: 1.4289x; 1.4289x over previous
//
#include <hip/hip_runtime.h>

#define P_N    20000
#define D_N    10000
#define R_N    64
#define EPER_N 16384
#define EDD_N  (R_N*EPER_N)
#define EPP_N  640000
#define EDP_N  160000
#define NE_N   48
#define PD_N   16
#define IN1_N  64   // NE+PD
#define NH1_N  32
#define NH2_N  16
#define GH1_N  32
#define GH2_N  16

static __device__ __forceinline__ int gtid() { return blockIdx.x * blockDim.x + threadIdx.x; }

// ---------- CSR build ----------
__global__ void k_hist(const int* __restrict__ dst, int E, int off, int* __restrict__ cnt) {
    int i = gtid();
    if (i < E) atomicAdd(&cnt[dst[i] - off], 1);
}

// single-block exclusive scan (1024 thr, wave-shuffle); writes start[] and cursor[]
__global__ __launch_bounds__(1024) void k_scan(const int* __restrict__ cnt, int n,
                                               int* __restrict__ start, int* __restrict__ cursor) {
    __shared__ int wsum[16];
    __shared__ int carrySh, totSh;
    int lane = threadIdx.x & 63, wid = threadIdx.x >> 6;
    if (threadIdx.x == 0) carrySh = 0;
    __syncthreads();
    for (int base = 0; base < n; base += 1024) {
        int i = base + threadIdx.x;
        int v = (i < n) ? cnt[i] : 0;
        int s = v;
#pragma unroll
        for (int ofs = 1; ofs < 64; ofs <<= 1) {
            int t = __shfl_up(s, ofs);
            if (lane >= ofs) s += t;
        }
        if (lane == 63) wsum[wid] = s;
        __syncthreads();
        if (threadIdx.x == 0) {
            int run = 0;
#pragma unroll
            for (int k = 0; k < 16; ++k) { int t = wsum[k]; wsum[k] = run; run += t; }
            totSh = run;
        }
        __syncthreads();
        int excl = carrySh + wsum[wid] + (s - v);
        if (i < n) { start[i] = excl; cursor[i] = excl; }
        __syncthreads();
        if (threadIdx.x == 0) carrySh += totSh;
        __syncthreads();
    }
}

// pos[e] = absolute sorted slot (cursor pre-loaded with start)
__global__ void k_rank(const int* __restrict__ dst, int E, int off,
                       int* __restrict__ cursor, int* __restrict__ pos) {
    int i = gtid();
    if (i < E) pos[i] = atomicAdd(&cursor[dst[i] - off], 1);
}

// srcs[slot] = src[e]  (payload permute for gather-only aggregations)
__global__ void k_permute_src(const int* __restrict__ src, const int* __restrict__ dst, int E, int off,
                              int* __restrict__ cursor, int* __restrict__ srcs) {
    int i = gtid();
    if (i < E) srcs[atomicAdd(&cursor[dst[i] - off], 1)] = src[i];
}

__global__ void k_dinv(const int* __restrict__ cnt, float* __restrict__ dinv, int n) {
    int i = gtid();
    if (i < n) dinv[i] = rsqrtf((float)cnt[i] + 1.0f);
}

// ---------- dense helpers ----------
template<int K, int N>
__global__ void k_matmul(const float* __restrict__ A, const float* __restrict__ W,
                         float* __restrict__ C, int M) {
    int id = gtid();
    if (id >= M * N) return;
    int m = id / N, n = id % N;
    const float* a = A + (size_t)m * K;
    float acc = 0.f;
#pragma unroll
    for (int k = 0; k < K; ++k) acc = fmaf(a[k], W[k * N + n], acc);
    C[id] = acc;
}

// GCN aggregate (gather form): out[d] = dinv[d]*sum_e h[s]*dinv[s] + h[d]*dinv[d]^2 + b (+relu)
template<int N>
__global__ __launch_bounds__(256) void k_gcn_gather(const float* __restrict__ h, const float* __restrict__ dinv,
                                                    const int* __restrict__ srcs, const int* __restrict__ start,
                                                    const int* __restrict__ cnt, const float* __restrict__ b,
                                                    float* __restrict__ out, int M, int relu) {
    int g = blockIdx.x * (256 / N) + threadIdx.x / N;
    int c = threadIdx.x % N;
    if (g >= M) return;
    int s0 = start[g], n = cnt[g];
    float acc = 0.f;
    for (int i = s0; i < s0 + n; ++i) {
        int s = srcs[i];
        acc = fmaf(h[(size_t)s * N + c], dinv[s], acc);
    }
    float di = dinv[g];
    float v = acc * di + h[(size_t)g * N + c] * di * di + b[c];
    out[(size_t)g * N + c] = relu ? fmaxf(v, 0.f) : v;
}

// prot->drug mean + 16x16 projection, fused; writes xcat[:,48:64]
__global__ __launch_bounds__(256) void k_dp_gather(const float* __restrict__ hp, const int* __restrict__ srcs,
                                                   const int* __restrict__ start, const int* __restrict__ cnt,
                                                   const float* __restrict__ w, float* __restrict__ xcat) {
    __shared__ float mean[16][17];
    int lg = threadIdx.x / 16, c = threadIdx.x % 16;
    int d = blockIdx.x * 16 + lg;
    float acc = 0.f;
    int n = 0;
    if (d < D_N) {
        int s0 = start[d]; n = cnt[d];
        for (int i = s0; i < s0 + n; ++i) acc += hp[(size_t)srcs[i] * PD_N + c];
        acc /= fmaxf((float)n, 1.f);
    }
    mean[lg][c] = acc;
    __syncthreads();
    if (d < D_N) {
        float o = 0.f;
#pragma unroll
        for (int k = 0; k < PD_N; ++k) o = fmaf(mean[lg][k], w[k * PD_N + c], o);
        xcat[(size_t)d * IN1_N + NE_N + c] = o;
    }
}

// xcat[:,0:48] = (x_drug @ embed) / d_norm ; LDS-tiled
#define EMB_BM 16
__global__ __launch_bounds__(256) void k_embed(const float* __restrict__ xd,
                                               const float* __restrict__ emb,
                                               const float* __restrict__ dnorm,
                                               float* __restrict__ xcat) {
    __shared__ float es[64][48];
    __shared__ float xs[EMB_BM][65];
    int tid = threadIdx.x;
    int row0 = blockIdx.x * EMB_BM;
    int r = tid / 16, cg = tid % 16;
    float acc0 = 0.f, acc1 = 0.f, acc2 = 0.f;
    for (int k0 = 0; k0 < 2048; k0 += 64) {
        __syncthreads();
        for (int i = tid; i < 64 * 48; i += 256) es[i / 48][i % 48] = emb[(size_t)(k0 + i / 48) * 48 + i % 48];
        for (int i = tid; i < EMB_BM * 64; i += 256) {
            int rr = i / 64, kk = i % 64;
            int grow = row0 + rr;
            xs[rr][kk] = (grow < D_N) ? xd[(size_t)grow * 2048 + k0 + kk] : 0.f;
        }
        __syncthreads();
#pragma unroll
        for (int k = 0; k < 64; ++k) {
            float xv = xs[r][k];
            acc0 = fmaf(xv, es[k][cg * 3 + 0], acc0);
            acc1 = fmaf(xv, es[k][cg * 3 + 1], acc1);
            acc2 = fmaf(xv, es[k][cg * 3 + 2], acc2);
        }
    }
    int grow = row0 + r;
    if (grow < D_N) {
        float inv = 1.0f / dnorm[grow];
        xcat[grow * IN1_N + cg * 3 + 0] = acc0 * inv;
        xcat[grow * IN1_N + cg * 3 + 1] = acc1 * inv;
        xcat[grow * IN1_N + cg * 3 + 2] = acc2 * inv;
    }
}

__global__ void k_rgcn_w(const float* __restrict__ att, const float* __restrict__ basis,
                         float* __restrict__ W, int IO) {
    int id = gtid();
    if (id >= R_N * IO) return;
    int r = id / IO, io = id % IO;
    float acc = 0.f;
#pragma unroll
    for (int b = 0; b < 32; ++b) acc = fmaf(att[r * 32 + b], basis[b * IO + io], acc);
    W[id] = acc;
}

// per-edge msg = x[src] @ W[rel], stored at dst-sorted slot pos[e] (NO atomics)
template<int IN, int OUT>
__global__ __launch_bounds__(256) void k_rgcn_msg(const float* __restrict__ x,
                                                  const int* __restrict__ src,
                                                  const int* __restrict__ pos,
                                                  const float* __restrict__ Wall,
                                                  float* __restrict__ msg) {
    constexpr int CPT = 4;
    constexpr int GP  = OUT / CPT;
    constexpr int EPI = 256 / GP;
    constexpr int EB  = 2 * EPI;
    __shared__ float ws[IN * OUT];
    int tid = threadIdx.x;
    int e0 = blockIdx.x * EB;
    int rel = e0 >> 14;               // /EPER; EB divides EPER
    for (int i = tid; i < IN * OUT; i += 256) ws[i] = Wall[rel * IN * OUT + i];
    __syncthreads();
    int c0 = (tid % GP) * CPT;
    int el = tid / GP;
    int ea = e0 + el, eb = e0 + EPI + el;
    int sa = src[ea], sb = src[eb];
    const float4* xa = (const float4*)(x + (size_t)sa * IN);
    const float4* xb = (const float4*)(x + (size_t)sb * IN);
    float acca[4] = {0.f, 0.f, 0.f, 0.f};
    float accb[4] = {0.f, 0.f, 0.f, 0.f};
#pragma unroll
    for (int k4 = 0; k4 < IN / 4; ++k4) {
        float4 va = xa[k4], vb = xb[k4];
#pragma unroll
        for (int kk = 0; kk < 4; ++kk) {
            int k = k4 * 4 + kk;
            float4 w = *(const float4*)&ws[k * OUT + c0];
            float fa = kk == 0 ? va.x : kk == 1 ? va.y : kk == 2 ? va.z : va.w;
            float fb = kk == 0 ? vb.x : kk == 1 ? vb.y : kk == 2 ? vb.z : vb.w;
            acca[0] = fmaf(fa, w.x, acca[0]); acca[1] = fmaf(fa, w.y, acca[1]);
            acca[2] = fmaf(fa, w.z, acca[2]); acca[3] = fmaf(fa, w.w, acca[3]);
            accb[0] = fmaf(fb, w.x, accb[0]); accb[1] = fmaf(fb, w.y, accb[1]);
            accb[2] = fmaf(fb, w.z, accb[2]); accb[3] = fmaf(fb, w.w, accb[3]);
        }
    }
    int pa = pos[ea], pb = pos[eb];
    *(float4*)&msg[(size_t)pa * OUT + c0] = make_float4(acca[0], acca[1], acca[2], acca[3]);
    *(float4*)&msg[(size_t)pb * OUT + c0] = make_float4(accb[0], accb[1], accb[2], accb[3]);
}

// out[d] = mean(msg segment) + x[d] @ root (+relu); msg is dst-sorted -> streaming reads
template<int IN, int OUT>
__global__ __launch_bounds__(256) void k_rgcn_gather(const float* __restrict__ msg,
                                                     const int* __restrict__ start, const int* __restrict__ cnt,
                                                     const float* __restrict__ x, const float* __restrict__ root,
                                                     float* __restrict__ out, int relu) {
    int g = blockIdx.x * (256 / OUT) + threadIdx.x / OUT;
    int c = threadIdx.x % OUT;
    if (g >= D_N) return;
    int s0 = start[g], n = cnt[g];
    float acc = 0.f;
    for (int i = s0; i < s0 + n; ++i) acc += msg[(size_t)i * OUT + c];
    acc /= fmaxf((float)n, 1.f);
#pragma unroll
    for (int k = 0; k < IN; ++k) acc = fmaf(x[(size_t)g * IN + k], root[k * OUT + c], acc);
    out[(size_t)g * OUT + c] = relu ? fmaxf(acc, 0.f) : acc;
}

extern "C" void kernel_launch(void* const* d_in, const int* in_sizes, int n_in,
                              void* d_out, int out_size, void* d_ws, size_t ws_size,
                              hipStream_t stream) {
    const float* x_drug   = (const float*)d_in[0];
    const int*   dd_ei    = (const int*)d_in[1];
    const float* d_norm   = (const float*)d_in[4];
    const float* x_prot   = (const float*)d_in[5];
    const int*   pp_ei    = (const int*)d_in[6];
    const int*   dp_ei    = (const int*)d_in[7];
    const float* gcn_w1   = (const float*)d_in[9];
    const float* gcn_b1   = (const float*)d_in[10];
    const float* gcn_w2   = (const float*)d_in[11];
    const float* gcn_b2   = (const float*)d_in[12];
    const float* embed    = (const float*)d_in[13];
    const float* hgcn_w   = (const float*)d_in[14];
    const float* r1_basis = (const float*)d_in[15];
    const float* r1_att   = (const float*)d_in[16];
    const float* r1_root  = (const float*)d_in[17];
    const float* r2_basis = (const float*)d_in[18];
    const float* r2_att   = (const float*)d_in[19];
    const float* r2_root  = (const float*)d_in[20];
    float* out = (float*)d_out;

    char* ws = (char*)d_ws;
    size_t off = 0;
    auto alloci = [&](size_t n) { int* p = (int*)(ws + off); off += ((n * 4 + 255) & ~(size_t)255); return p; };
    auto allocf = [&](size_t n) { float* p = (float*)(ws + off); off += ((n * 4 + 255) & ~(size_t)255); return p; };
    // ---- zeroed region: the three histograms ----
    int* pp_cnt = alloci(P_N);
    int* dd_cnt = alloci(D_N);
    int* dp_cnt = alloci(D_N);
    size_t zbytes = off;
    // ---- scratch (written before read) ----
    int* pp_start = alloci(P_N);  int* pp_cur = alloci(P_N);  int* pp_srcs = alloci(EPP_N);
    int* dd_start = alloci(D_N);  int* dd_cur = alloci(D_N);  int* dd_pos  = alloci(EDD_N);
    int* dp_start = alloci(D_N);  int* dp_cur = alloci(D_N);  int* dp_srcs = alloci(EDP_N);
    float* dinv = allocf(P_N);
    float* h1   = allocf((size_t)P_N * GH1_N);
    float* agg1 = allocf((size_t)P_N * GH1_N);
    float* h2   = allocf((size_t)P_N * GH2_N);
    float* agg2 = allocf((size_t)P_N * GH2_N);
    float* xcat = allocf((size_t)D_N * IN1_N);
    float* W1   = allocf((size_t)R_N * IN1_N * NH1_N);
    float* W2   = allocf((size_t)R_N * NH1_N * NH2_N);
    float* h1d  = allocf((size_t)D_N * NH1_N);
    float* msg  = allocf((size_t)EDD_N * NH1_N);   // 134 MB; reused by layer 2 (67 MB)

    hipMemsetAsync(d_ws, 0, zbytes, stream);

    auto g = [](int n) { return (n + 255) / 256; };
    const int *pp_src = pp_ei, *pp_dst = pp_ei + EPP_N;
    const int *dd_src = dd_ei, *dd_dst = dd_ei + EDD_N;
    const int *dp_src = dp_ei, *dp_dst = dp_ei + EDP_N;

    // ---- CSR builds (int atomics only) ----
    k_hist<<<g(EPP_N), 256, 0, stream>>>(pp_dst, EPP_N, 0, pp_cnt);
    k_hist<<<g(EDD_N), 256, 0, stream>>>(dd_dst, EDD_N, 0, dd_cnt);
    k_hist<<<g(EDP_N), 256, 0, stream>>>(dp_dst, EDP_N, P_N, dp_cnt);
    k_scan<<<1, 1024, 0, stream>>>(pp_cnt, P_N, pp_start, pp_cur);
    k_scan<<<1, 1024, 0, stream>>>(dd_cnt, D_N, dd_start, dd_cur);
    k_scan<<<1, 1024, 0, stream>>>(dp_cnt, D_N, dp_start, dp_cur);
    k_permute_src<<<g(EPP_N), 256, 0, stream>>>(pp_src, pp_dst, EPP_N, 0, pp_cur, pp_srcs);
    k_rank<<<g(EDD_N), 256, 0, stream>>>(dd_dst, EDD_N, 0, dd_cur, dd_pos);
    k_permute_src<<<g(EDP_N), 256, 0, stream>>>(dp_src, dp_dst, EDP_N, P_N, dp_cur, dp_srcs);

    // ---- PPEncoder (gather form) ----
    k_dinv<<<g(P_N), 256, 0, stream>>>(pp_cnt, dinv, P_N);
    k_matmul<128, GH1_N><<<g(P_N * GH1_N), 256, 0, stream>>>(x_prot, gcn_w1, h1, P_N);
    k_gcn_gather<GH1_N><<<(P_N + 7) / 8, 256, 0, stream>>>(h1, dinv, pp_srcs, pp_start, pp_cnt, gcn_b1, agg1, P_N, 1);
    k_matmul<GH1_N, GH2_N><<<g(P_N * GH2_N), 256, 0, stream>>>(agg1, gcn_w2, h2, P_N);
    k_gcn_gather<GH2_N><<<(P_N + 15) / 16, 256, 0, stream>>>(h2, dinv, pp_srcs, pp_start, pp_cnt, gcn_b2, agg2, P_N, 0);

    // ---- hierarchy conv + drug embedding -> xcat ----
    k_dp_gather<<<(D_N + 15) / 16, 256, 0, stream>>>(agg2, dp_srcs, dp_start, dp_cnt, hgcn_w, xcat);
    k_embed<<<(D_N + EMB_BM - 1) / EMB_BM, 256, 0, stream>>>(x_drug, embed, d_norm, xcat);

    // ---- RGCN weights ----
    k_rgcn_w<<<g(R_N * IN1_N * NH1_N), 256, 0, stream>>>(r1_att, r1_basis, W1, IN1_N * NH1_N);
    k_rgcn_w<<<g(R_N * NH1_N * NH2_N), 256, 0, stream>>>(r2_att, r2_basis, W2, NH1_N * NH2_N);

    // ---- RGCN layer 1 (relu) ----
    k_rgcn_msg<IN1_N, NH1_N><<<EDD_N / 64, 256, 0, stream>>>(xcat, dd_src, dd_pos, W1, msg);
    k_rgcn_gather<IN1_N, NH1_N><<<(D_N + 7) / 8, 256, 0, stream>>>(msg, dd_start, dd_cnt, xcat, r1_root, h1d, 1);
    // ---- RGCN layer 2 (final) ----
    k_rgcn_msg<NH1_N, NH2_N><<<EDD_N / 128, 256, 0, stream>>>(h1d, dd_src, dd_pos, W2, msg);
    k_rgcn_gather<NH1_N, NH2_N><<<(D_N + 15) / 16, 256, 0, stream>>>(msg, dd_start, dd_cnt, h1d, r2_root, out, 0);
}

// Round 9
// 834.301 us; speedup vs baseline: 1.6225x; 1.1355x over previous
//
#include <hip/hip_runtime.h>

#define P_N    20000
#define D_N    10000
#define R_N    64
#define EPER_N 16384
#define EDD_N  (R_N*EPER_N)
#define EPP_N  640000
#define EDP_N  160000
#define NE_N   48
#define PD_N   16
#define IN1_N  64   // NE+PD
#define NH1_N  32
#define NH2_N  16
#define GH1_N  32
#define GH2_N  16
#define EMB_KS 4        // K-splits for the embed GEMM
#define EMB_KC (2048/EMB_KS)

static __device__ __forceinline__ int gtid() { return blockIdx.x * blockDim.x + threadIdx.x; }

// ---------- CSR build ----------
__global__ void k_hist(const int* __restrict__ dst, int E, int off, int* __restrict__ cnt) {
    int i = gtid();
    if (i < E) atomicAdd(&cnt[dst[i] - off], 1);
}

// single-block exclusive scan (1024 thr, wave-shuffle); writes start[] and cursor[]
__global__ __launch_bounds__(1024) void k_scan(const int* __restrict__ cnt, int n,
                                               int* __restrict__ start, int* __restrict__ cursor) {
    __shared__ int wsum[16];
    __shared__ int carrySh, totSh;
    int lane = threadIdx.x & 63, wid = threadIdx.x >> 6;
    if (threadIdx.x == 0) carrySh = 0;
    __syncthreads();
    for (int base = 0; base < n; base += 1024) {
        int i = base + threadIdx.x;
        int v = (i < n) ? cnt[i] : 0;
        int s = v;
#pragma unroll
        for (int ofs = 1; ofs < 64; ofs <<= 1) {
            int t = __shfl_up(s, ofs);
            if (lane >= ofs) s += t;
        }
        if (lane == 63) wsum[wid] = s;
        __syncthreads();
        if (threadIdx.x == 0) {
            int run = 0;
#pragma unroll
            for (int k = 0; k < 16; ++k) { int t = wsum[k]; wsum[k] = run; run += t; }
            totSh = run;
        }
        __syncthreads();
        int excl = carrySh + wsum[wid] + (s - v);
        if (i < n) { start[i] = excl; cursor[i] = excl; }
        __syncthreads();
        if (threadIdx.x == 0) carrySh += totSh;
        __syncthreads();
    }
}

// pos[e] = absolute sorted slot (cursor pre-loaded with start)
__global__ void k_rank(const int* __restrict__ dst, int E, int off,
                       int* __restrict__ cursor, int* __restrict__ pos) {
    int i = gtid();
    if (i < E) pos[i] = atomicAdd(&cursor[dst[i] - off], 1);
}

// srcs[slot] = src[e]  (payload permute for gather-only aggregations)
__global__ void k_permute_src(const int* __restrict__ src, const int* __restrict__ dst, int E, int off,
                              int* __restrict__ cursor, int* __restrict__ srcs) {
    int i = gtid();
    if (i < E) srcs[atomicAdd(&cursor[dst[i] - off], 1)] = src[i];
}

__global__ void k_dinv(const int* __restrict__ cnt, float* __restrict__ dinv, int n) {
    int i = gtid();
    if (i < n) dinv[i] = rsqrtf((float)cnt[i] + 1.0f);
}

// ---------- dense helpers ----------
template<int K, int N>
__global__ void k_matmul(const float* __restrict__ A, const float* __restrict__ W,
                         float* __restrict__ C, int M) {
    int id = gtid();
    if (id >= M * N) return;
    int m = id / N, n = id % N;
    const float* a = A + (size_t)m * K;
    float acc = 0.f;
#pragma unroll
    for (int k = 0; k < K; ++k) acc = fmaf(a[k], W[k * N + n], acc);
    C[id] = acc;
}

// GCN aggregate (gather form): out[d] = dinv[d]*sum_e h[s]*dinv[s] + h[d]*dinv[d]^2 + b (+relu)
template<int N>
__global__ __launch_bounds__(256) void k_gcn_gather(const float* __restrict__ h, const float* __restrict__ dinv,
                                                    const int* __restrict__ srcs, const int* __restrict__ start,
                                                    const int* __restrict__ cnt, const float* __restrict__ b,
                                                    float* __restrict__ out, int M, int relu) {
    int g = blockIdx.x * (256 / N) + threadIdx.x / N;
    int c = threadIdx.x % N;
    if (g >= M) return;
    int s0 = start[g], n = cnt[g];
    float acc = 0.f;
    for (int i = s0; i < s0 + n; ++i) {
        int s = srcs[i];
        acc = fmaf(h[(size_t)s * N + c], dinv[s], acc);
    }
    float di = dinv[g];
    float v = acc * di + h[(size_t)g * N + c] * di * di + b[c];
    out[(size_t)g * N + c] = relu ? fmaxf(v, 0.f) : v;
}

// prot->drug mean + 16x16 projection, fused; writes xcat[:,48:64]
__global__ __launch_bounds__(256) void k_dp_gather(const float* __restrict__ hp, const int* __restrict__ srcs,
                                                   const int* __restrict__ start, const int* __restrict__ cnt,
                                                   const float* __restrict__ w, float* __restrict__ xcat) {
    __shared__ float mean[16][17];
    int lg = threadIdx.x / 16, c = threadIdx.x % 16;
    int d = blockIdx.x * 16 + lg;
    float acc = 0.f;
    int n = 0;
    if (d < D_N) {
        int s0 = start[d]; n = cnt[d];
        for (int i = s0; i < s0 + n; ++i) acc += hp[(size_t)srcs[i] * PD_N + c];
        acc /= fmaxf((float)n, 1.f);
    }
    mean[lg][c] = acc;
    __syncthreads();
    if (d < D_N) {
        float o = 0.f;
#pragma unroll
        for (int k = 0; k < PD_N; ++k) o = fmaf(mean[lg][k], w[k * PD_N + c], o);
        xcat[(size_t)d * IN1_N + NE_N + c] = o;
    }
}

// embed GEMM, K-split: pbuf[ks][d][c] = x_drug[d, ksK:(ks+1)K] @ embed[ksK:(ks+1)K, c]
// 16 rows/block, 48 cols; emb K-chunk is CONTIGUOUS (row-major [2048][48]) -> flat stage.
__global__ __launch_bounds__(256) void k_embed_part(const float* __restrict__ xd,
                                                    const float* __restrict__ emb,
                                                    float* __restrict__ pbuf) {
    __shared__ float es[64 * 48];
    __shared__ float xs[16][68];   // pad 68: float4-aligned, 2-way banks (free)
    int tid = threadIdx.x;
    int row0 = blockIdx.x * 16;
    int kbase = blockIdx.y * EMB_KC;
    int r = tid / 16, cg = tid % 16;
    int srr = tid >> 4, sc4 = tid & 15;
    float acc0 = 0.f, acc1 = 0.f, acc2 = 0.f;
    for (int k0 = kbase; k0 < kbase + EMB_KC; k0 += 64) {
        __syncthreads();
        for (int i = tid; i < 64 * 48; i += 256) es[i] = emb[(size_t)k0 * 48 + i];
        {   // stage 16 rows x 64 k as float4: thread -> (row srr, chunk sc4)
            float4 v = *(const float4*)&xd[(size_t)(row0 + srr) * 2048 + k0 + 4 * sc4];
            xs[srr][4 * sc4 + 0] = v.x; xs[srr][4 * sc4 + 1] = v.y;
            xs[srr][4 * sc4 + 2] = v.z; xs[srr][4 * sc4 + 3] = v.w;
        }
        __syncthreads();
#pragma unroll
        for (int k = 0; k < 64; ++k) {
            float xv = xs[r][k];
            acc0 = fmaf(xv, es[k * 48 + cg * 3 + 0], acc0);
            acc1 = fmaf(xv, es[k * 48 + cg * 3 + 1], acc1);
            acc2 = fmaf(xv, es[k * 48 + cg * 3 + 2], acc2);
        }
    }
    size_t o = ((size_t)blockIdx.y * D_N + row0 + r) * 48 + cg * 3;
    pbuf[o + 0] = acc0; pbuf[o + 1] = acc1; pbuf[o + 2] = acc2;
}

// xcat[:,0:48] = (sum of EMB_KS partials) / d_norm
__global__ void k_embed_reduce(const float* __restrict__ pbuf, const float* __restrict__ dnorm,
                               float* __restrict__ xcat) {
    int id = gtid();
    if (id >= D_N * 48) return;
    int d = id / 48, c = id % 48;
    float acc = 0.f;
#pragma unroll
    for (int ks = 0; ks < EMB_KS; ++ks) acc += pbuf[((size_t)ks * D_N + d) * 48 + c];
    xcat[(size_t)d * IN1_N + c] = acc / dnorm[d];
}

__global__ void k_rgcn_w(const float* __restrict__ att, const float* __restrict__ basis,
                         float* __restrict__ W, int IO) {
    int id = gtid();
    if (id >= R_N * IO) return;
    int r = id / IO, io = id % IO;
    float acc = 0.f;
#pragma unroll
    for (int b = 0; b < 32; ++b) acc = fmaf(att[r * 32 + b], basis[b * IO + io], acc);
    W[id] = acc;
}

// per-edge msg = x[src] @ W[rel], stored at dst-sorted slot pos[e] (NO atomics)
template<int IN, int OUT>
__global__ __launch_bounds__(256) void k_rgcn_msg(const float* __restrict__ x,
                                                  const int* __restrict__ src,
                                                  const int* __restrict__ pos,
                                                  const float* __restrict__ Wall,
                                                  float* __restrict__ msg) {
    constexpr int CPT = 4;
    constexpr int GP  = OUT / CPT;
    constexpr int EPI = 256 / GP;
    constexpr int EB  = 2 * EPI;
    __shared__ float ws[IN * OUT];
    int tid = threadIdx.x;
    int e0 = blockIdx.x * EB;
    int rel = e0 >> 14;               // /EPER; EB divides EPER
    for (int i = tid; i < IN * OUT; i += 256) ws[i] = Wall[rel * IN * OUT + i];
    __syncthreads();
    int c0 = (tid % GP) * CPT;
    int el = tid / GP;
    int ea = e0 + el, eb = e0 + EPI + el;
    int sa = src[ea], sb = src[eb];
    const float4* xa = (const float4*)(x + (size_t)sa * IN);
    const float4* xb = (const float4*)(x + (size_t)sb * IN);
    float acca[4] = {0.f, 0.f, 0.f, 0.f};
    float accb[4] = {0.f, 0.f, 0.f, 0.f};
#pragma unroll
    for (int k4 = 0; k4 < IN / 4; ++k4) {
        float4 va = xa[k4], vb = xb[k4];
#pragma unroll
        for (int kk = 0; kk < 4; ++kk) {
            int k = k4 * 4 + kk;
            float4 w = *(const float4*)&ws[k * OUT + c0];
            float fa = kk == 0 ? va.x : kk == 1 ? va.y : kk == 2 ? va.z : va.w;
            float fb = kk == 0 ? vb.x : kk == 1 ? vb.y : kk == 2 ? vb.z : vb.w;
            acca[0] = fmaf(fa, w.x, acca[0]); acca[1] = fmaf(fa, w.y, acca[1]);
            acca[2] = fmaf(fa, w.z, acca[2]); acca[3] = fmaf(fa, w.w, acca[3]);
            accb[0] = fmaf(fb, w.x, accb[0]); accb[1] = fmaf(fb, w.y, accb[1]);
            accb[2] = fmaf(fb, w.z, accb[2]); accb[3] = fmaf(fb, w.w, accb[3]);
        }
    }
    int pa = pos[ea], pb = pos[eb];
    *(float4*)&msg[(size_t)pa * OUT + c0] = make_float4(acca[0], acca[1], acca[2], acca[3]);
    *(float4*)&msg[(size_t)pb * OUT + c0] = make_float4(accb[0], accb[1], accb[2], accb[3]);
}

// out[d] = mean(msg segment) + x[d] @ root (+relu); msg is dst-sorted -> streaming reads
template<int IN, int OUT>
__global__ __launch_bounds__(256) void k_rgcn_gather(const float* __restrict__ msg,
                                                     const int* __restrict__ start, const int* __restrict__ cnt,
                                                     const float* __restrict__ x, const float* __restrict__ root,
                                                     float* __restrict__ out, int relu) {
    int g = blockIdx.x * (256 / OUT) + threadIdx.x / OUT;
    int c = threadIdx.x % OUT;
    if (g >= D_N) return;
    int s0 = start[g], n = cnt[g];
    float acc = 0.f;
    for (int i = s0; i < s0 + n; ++i) acc += msg[(size_t)i * OUT + c];
    acc /= fmaxf((float)n, 1.f);
#pragma unroll
    for (int k = 0; k < IN; ++k) acc = fmaf(x[(size_t)g * IN + k], root[k * OUT + c], acc);
    out[(size_t)g * OUT + c] = relu ? fmaxf(acc, 0.f) : acc;
}

extern "C" void kernel_launch(void* const* d_in, const int* in_sizes, int n_in,
                              void* d_out, int out_size, void* d_ws, size_t ws_size,
                              hipStream_t stream) {
    const float* x_drug   = (const float*)d_in[0];
    const int*   dd_ei    = (const int*)d_in[1];
    const float* d_norm   = (const float*)d_in[4];
    const float* x_prot   = (const float*)d_in[5];
    const int*   pp_ei    = (const int*)d_in[6];
    const int*   dp_ei    = (const int*)d_in[7];
    const float* gcn_w1   = (const float*)d_in[9];
    const float* gcn_b1   = (const float*)d_in[10];
    const float* gcn_w2   = (const float*)d_in[11];
    const float* gcn_b2   = (const float*)d_in[12];
    const float* embed    = (const float*)d_in[13];
    const float* hgcn_w   = (const float*)d_in[14];
    const float* r1_basis = (const float*)d_in[15];
    const float* r1_att   = (const float*)d_in[16];
    const float* r1_root  = (const float*)d_in[17];
    const float* r2_basis = (const float*)d_in[18];
    const float* r2_att   = (const float*)d_in[19];
    const float* r2_root  = (const float*)d_in[20];
    float* out = (float*)d_out;

    char* ws = (char*)d_ws;
    size_t off = 0;
    auto alloci = [&](size_t n) { int* p = (int*)(ws + off); off += ((n * 4 + 255) & ~(size_t)255); return p; };
    auto allocf = [&](size_t n) { float* p = (float*)(ws + off); off += ((n * 4 + 255) & ~(size_t)255); return p; };
    // ---- zeroed region: the three histograms ----
    int* pp_cnt = alloci(P_N);
    int* dd_cnt = alloci(D_N);
    int* dp_cnt = alloci(D_N);
    size_t zbytes = off;
    // ---- scratch (written before read) ----
    int* pp_start = alloci(P_N);  int* pp_cur = alloci(P_N);  int* pp_srcs = alloci(EPP_N);
    int* dd_start = alloci(D_N);  int* dd_cur = alloci(D_N);  int* dd_pos  = alloci(EDD_N);
    int* dp_start = alloci(D_N);  int* dp_cur = alloci(D_N);  int* dp_srcs = alloci(EDP_N);
    float* dinv = allocf(P_N);
    float* h1   = allocf((size_t)P_N * GH1_N);
    float* agg1 = allocf((size_t)P_N * GH1_N);
    float* h2   = allocf((size_t)P_N * GH2_N);
    float* agg2 = allocf((size_t)P_N * GH2_N);
    float* xcat = allocf((size_t)D_N * IN1_N);
    float* W1   = allocf((size_t)R_N * IN1_N * NH1_N);
    float* W2   = allocf((size_t)R_N * NH1_N * NH2_N);
    float* h1d  = allocf((size_t)D_N * NH1_N);
    float* pbuf = allocf((size_t)EMB_KS * D_N * 48);   // embed partials (7.7 MB)
    float* msg  = allocf((size_t)EDD_N * NH1_N);       // 134 MB; reused by layer 2

    hipMemsetAsync(d_ws, 0, zbytes, stream);

    auto g = [](int n) { return (n + 255) / 256; };
    const int *pp_src = pp_ei, *pp_dst = pp_ei + EPP_N;
    const int *dd_src = dd_ei, *dd_dst = dd_ei + EDD_N;
    const int *dp_src = dp_ei, *dp_dst = dp_ei + EDP_N;

    // ---- CSR builds (int atomics only) ----
    k_hist<<<g(EPP_N), 256, 0, stream>>>(pp_dst, EPP_N, 0, pp_cnt);
    k_hist<<<g(EDD_N), 256, 0, stream>>>(dd_dst, EDD_N, 0, dd_cnt);
    k_hist<<<g(EDP_N), 256, 0, stream>>>(dp_dst, EDP_N, P_N, dp_cnt);
    k_scan<<<1, 1024, 0, stream>>>(pp_cnt, P_N, pp_start, pp_cur);
    k_scan<<<1, 1024, 0, stream>>>(dd_cnt, D_N, dd_start, dd_cur);
    k_scan<<<1, 1024, 0, stream>>>(dp_cnt, D_N, dp_start, dp_cur);
    k_permute_src<<<g(EPP_N), 256, 0, stream>>>(pp_src, pp_dst, EPP_N, 0, pp_cur, pp_srcs);
    k_rank<<<g(EDD_N), 256, 0, stream>>>(dd_dst, EDD_N, 0, dd_cur, dd_pos);
    k_permute_src<<<g(EDP_N), 256, 0, stream>>>(dp_src, dp_dst, EDP_N, P_N, dp_cur, dp_srcs);

    // ---- PPEncoder (gather form) ----
    k_dinv<<<g(P_N), 256, 0, stream>>>(pp_cnt, dinv, P_N);
    k_matmul<128, GH1_N><<<g(P_N * GH1_N), 256, 0, stream>>>(x_prot, gcn_w1, h1, P_N);
    k_gcn_gather<GH1_N><<<(P_N + 7) / 8, 256, 0, stream>>>(h1, dinv, pp_srcs, pp_start, pp_cnt, gcn_b1, agg1, P_N, 1);
    k_matmul<GH1_N, GH2_N><<<g(P_N * GH2_N), 256, 0, stream>>>(agg1, gcn_w2, h2, P_N);
    k_gcn_gather<GH2_N><<<(P_N + 15) / 16, 256, 0, stream>>>(h2, dinv, pp_srcs, pp_start, pp_cnt, gcn_b2, agg2, P_N, 0);

    // ---- hierarchy conv + drug embedding -> xcat ----
    k_dp_gather<<<(D_N + 15) / 16, 256, 0, stream>>>(agg2, dp_srcs, dp_start, dp_cnt, hgcn_w, xcat);
    k_embed_part<<<dim3(D_N / 16, EMB_KS), 256, 0, stream>>>(x_drug, embed, pbuf);
    k_embed_reduce<<<g(D_N * 48), 256, 0, stream>>>(pbuf, d_norm, xcat);

    // ---- RGCN weights ----
    k_rgcn_w<<<g(R_N * IN1_N * NH1_N), 256, 0, stream>>>(r1_att, r1_basis, W1, IN1_N * NH1_N);
    k_rgcn_w<<<g(R_N * NH1_N * NH2_N), 256, 0, stream>>>(r2_att, r2_basis, W2, NH1_N * NH2_N);

    // ---- RGCN layer 1 (relu) ----
    k_rgcn_msg<IN1_N, NH1_N><<<EDD_N / 64, 256, 0, stream>>>(xcat, dd_src, dd_pos, W1, msg);
    k_rgcn_gather<IN1_N, NH1_N><<<(D_N + 7) / 8, 256, 0, stream>>>(msg, dd_start, dd_cnt, xcat, r1_root, h1d, 1);
    // ---- RGCN layer 2 (final) ----
    k_rgcn_msg<NH1_N, NH2_N><<<EDD_N / 128, 256, 0, stream>>>(h1d, dd_src, dd_pos, W2, msg);
    k_rgcn_gather<NH1_N, NH2_N><<<(D_N + 15) / 16, 256, 0, stream>>>(msg, dd_start, dd_cnt, h1d, r2_root, out, 0);
}

// Round 10
// 757.935 us; speedup vs baseline: 1.7860x; 1.1008x over previous
//
#include <hip/hip_runtime.h>

#define P_N    20000
#define D_N    10000
#define R_N    64
#define EPER_N 16384
#define EDD_N  (R_N*EPER_N)
#define EPP_N  640000
#define EDP_N  160000
#define NE_N   48
#define PD_N   16
#define IN1_N  64   // NE+PD
#define NH1_N  32
#define NH2_N  16
#define GH1_N  32
#define GH2_N  16
#define EMB_KS 8            // K-splits for the embed GEMM
#define EMB_KC (2048/EMB_KS)
#define EMB_BR 64           // rows per block

static __device__ __forceinline__ int gtid() { return blockIdx.x * blockDim.x + threadIdx.x; }

// ---------- CSR build ----------
__global__ void k_hist(const int* __restrict__ dst, int E, int off, int* __restrict__ cnt) {
    int i = gtid();
    if (i < E) atomicAdd(&cnt[dst[i] - off], 1);
}

// single-block exclusive scan (1024 thr, wave-shuffle); writes start[] and cursor[]
__global__ __launch_bounds__(1024) void k_scan(const int* __restrict__ cnt, int n,
                                               int* __restrict__ start, int* __restrict__ cursor) {
    __shared__ int wsum[16];
    __shared__ int carrySh, totSh;
    int lane = threadIdx.x & 63, wid = threadIdx.x >> 6;
    if (threadIdx.x == 0) carrySh = 0;
    __syncthreads();
    for (int base = 0; base < n; base += 1024) {
        int i = base + threadIdx.x;
        int v = (i < n) ? cnt[i] : 0;
        int s = v;
#pragma unroll
        for (int ofs = 1; ofs < 64; ofs <<= 1) {
            int t = __shfl_up(s, ofs);
            if (lane >= ofs) s += t;
        }
        if (lane == 63) wsum[wid] = s;
        __syncthreads();
        if (threadIdx.x == 0) {
            int run = 0;
#pragma unroll
            for (int k = 0; k < 16; ++k) { int t = wsum[k]; wsum[k] = run; run += t; }
            totSh = run;
        }
        __syncthreads();
        int excl = carrySh + wsum[wid] + (s - v);
        if (i < n) { start[i] = excl; cursor[i] = excl; }
        __syncthreads();
        if (threadIdx.x == 0) carrySh += totSh;
        __syncthreads();
    }
}

// pos[e] = absolute sorted slot (cursor pre-loaded with start)
__global__ void k_rank(const int* __restrict__ dst, int E, int off,
                       int* __restrict__ cursor, int* __restrict__ pos) {
    int i = gtid();
    if (i < E) pos[i] = atomicAdd(&cursor[dst[i] - off], 1);
}

// srcs[slot] = src[e]  (payload permute for gather-only aggregations)
__global__ void k_permute_src(const int* __restrict__ src, const int* __restrict__ dst, int E, int off,
                              int* __restrict__ cursor, int* __restrict__ srcs) {
    int i = gtid();
    if (i < E) srcs[atomicAdd(&cursor[dst[i] - off], 1)] = src[i];
}

__global__ void k_dinv(const int* __restrict__ cnt, float* __restrict__ dinv, int n) {
    int i = gtid();
    if (i < n) dinv[i] = rsqrtf((float)cnt[i] + 1.0f);
}

// ---------- dense helpers ----------
template<int K, int N>
__global__ void k_matmul(const float* __restrict__ A, const float* __restrict__ W,
                         float* __restrict__ C, int M) {
    int id = gtid();
    if (id >= M * N) return;
    int m = id / N, n = id % N;
    const float* a = A + (size_t)m * K;
    float acc = 0.f;
#pragma unroll
    for (int k = 0; k < K; ++k) acc = fmaf(a[k], W[k * N + n], acc);
    C[id] = acc;
}

// GCN aggregate (gather form): out[d] = dinv[d]*sum_e h[s]*dinv[s] + h[d]*dinv[d]^2 + b (+relu)
template<int N>
__global__ __launch_bounds__(256) void k_gcn_gather(const float* __restrict__ h, const float* __restrict__ dinv,
                                                    const int* __restrict__ srcs, const int* __restrict__ start,
                                                    const int* __restrict__ cnt, const float* __restrict__ b,
                                                    float* __restrict__ out, int M, int relu) {
    int g = blockIdx.x * (256 / N) + threadIdx.x / N;
    int c = threadIdx.x % N;
    if (g >= M) return;
    int s0 = start[g], n = cnt[g];
    float acc = 0.f;
    for (int i = s0; i < s0 + n; ++i) {
        int s = srcs[i];
        acc = fmaf(h[(size_t)s * N + c], dinv[s], acc);
    }
    float di = dinv[g];
    float v = acc * di + h[(size_t)g * N + c] * di * di + b[c];
    out[(size_t)g * N + c] = relu ? fmaxf(v, 0.f) : v;
}

// prot->drug mean + 16x16 projection, fused; writes xcat[:,48:64]
__global__ __launch_bounds__(256) void k_dp_gather(const float* __restrict__ hp, const int* __restrict__ srcs,
                                                   const int* __restrict__ start, const int* __restrict__ cnt,
                                                   const float* __restrict__ w, float* __restrict__ xcat) {
    __shared__ float mean[16][17];
    int lg = threadIdx.x / 16, c = threadIdx.x % 16;
    int d = blockIdx.x * 16 + lg;
    float acc = 0.f;
    int n = 0;
    if (d < D_N) {
        int s0 = start[d]; n = cnt[d];
        for (int i = s0; i < s0 + n; ++i) acc += hp[(size_t)srcs[i] * PD_N + c];
        acc /= fmaxf((float)n, 1.f);
    }
    mean[lg][c] = acc;
    __syncthreads();
    if (d < D_N) {
        float o = 0.f;
#pragma unroll
        for (int k = 0; k < PD_N; ++k) o = fmaf(mean[lg][k], w[k * PD_N + c], o);
        xcat[(size_t)d * IN1_N + NE_N + c] = o;
    }
}

// embed GEMM, K-split, register-blocked 4x4/thread.
// 64 rows x 48 cols per block, 192 threads (rowg=tid/12 -> 4 rows, colg=tid%12 -> 4 cols).
// Per 4-k step: 8 ds_read_b128 vs 64 FMA -> VALU-bound (was 4 b32 per 3 FMA).
__global__ __launch_bounds__(192) void k_embed_part(const float* __restrict__ xd,
                                                    const float* __restrict__ emb,
                                                    float* __restrict__ pbuf) {
    __shared__ float xs[EMB_BR][68];   // 64 k + pad (16B-aligned rows)
    __shared__ float es[64][48];       // row-major, col float4s contiguous
    int tid = threadIdx.x;
    int row0 = blockIdx.x * EMB_BR;
    int kbase = blockIdx.y * EMB_KC;
    int colg = tid % 12, rowg = tid / 12;   // rowg 0..15
    float4 acc[4] = {{0,0,0,0},{0,0,0,0},{0,0,0,0},{0,0,0,0}};
    for (int k0 = kbase; k0 < kbase + EMB_KC; k0 += 64) {
        __syncthreads();
        // stage es: 3072 floats = 768 float4 (emb chunk is contiguous, row-major [2048][48])
        for (int i = tid; i < 768; i += 192)
            ((float4*)es)[i] = ((const float4*)(emb + (size_t)k0 * 48))[i];
        // stage xs: 64 rows x 16 float4
        for (int i = tid; i < EMB_BR * 16; i += 192) {
            int rr = i / 16, f4 = i % 16;
            int grow = row0 + rr;
            float4 v = make_float4(0.f, 0.f, 0.f, 0.f);
            if (grow < D_N) v = *(const float4*)&xd[(size_t)grow * 2048 + k0 + 4 * f4];
            *(float4*)&xs[rr][4 * f4] = v;
        }
        __syncthreads();
#pragma unroll 4
        for (int ks = 0; ks < 16; ++ks) {
            float4 x0 = *(float4*)&xs[4 * rowg + 0][4 * ks];
            float4 x1 = *(float4*)&xs[4 * rowg + 1][4 * ks];
            float4 x2 = *(float4*)&xs[4 * rowg + 2][4 * ks];
            float4 x3 = *(float4*)&xs[4 * rowg + 3][4 * ks];
            float4 w0 = *(float4*)&es[4 * ks + 0][4 * colg];
            float4 w1 = *(float4*)&es[4 * ks + 1][4 * colg];
            float4 w2 = *(float4*)&es[4 * ks + 2][4 * colg];
            float4 w3 = *(float4*)&es[4 * ks + 3][4 * colg];
#define EMB_FMA(i, xv) \
            acc[i].x = fmaf(xv.x, w0.x, acc[i].x); acc[i].y = fmaf(xv.x, w0.y, acc[i].y); \
            acc[i].z = fmaf(xv.x, w0.z, acc[i].z); acc[i].w = fmaf(xv.x, w0.w, acc[i].w); \
            acc[i].x = fmaf(xv.y, w1.x, acc[i].x); acc[i].y = fmaf(xv.y, w1.y, acc[i].y); \
            acc[i].z = fmaf(xv.y, w1.z, acc[i].z); acc[i].w = fmaf(xv.y, w1.w, acc[i].w); \
            acc[i].x = fmaf(xv.z, w2.x, acc[i].x); acc[i].y = fmaf(xv.z, w2.y, acc[i].y); \
            acc[i].z = fmaf(xv.z, w2.z, acc[i].z); acc[i].w = fmaf(xv.z, w2.w, acc[i].w); \
            acc[i].x = fmaf(xv.w, w3.x, acc[i].x); acc[i].y = fmaf(xv.w, w3.y, acc[i].y); \
            acc[i].z = fmaf(xv.w, w3.z, acc[i].z); acc[i].w = fmaf(xv.w, w3.w, acc[i].w);
            EMB_FMA(0, x0) EMB_FMA(1, x1) EMB_FMA(2, x2) EMB_FMA(3, x3)
#undef EMB_FMA
        }
    }
#pragma unroll
    for (int i = 0; i < 4; ++i) {
        int grow = row0 + 4 * rowg + i;
        if (grow < D_N)
            *(float4*)&pbuf[((size_t)blockIdx.y * D_N + grow) * 48 + 4 * colg] = acc[i];
    }
}

// xcat[:,0:48] = (sum of EMB_KS partials) / d_norm
__global__ void k_embed_reduce(const float* __restrict__ pbuf, const float* __restrict__ dnorm,
                               float* __restrict__ xcat) {
    int id = gtid();
    if (id >= D_N * 48) return;
    int d = id / 48, c = id % 48;
    float acc = 0.f;
#pragma unroll
    for (int ks = 0; ks < EMB_KS; ++ks) acc += pbuf[((size_t)ks * D_N + d) * 48 + c];
    xcat[(size_t)d * IN1_N + c] = acc / dnorm[d];
}

__global__ void k_rgcn_w(const float* __restrict__ att, const float* __restrict__ basis,
                         float* __restrict__ W, int IO) {
    int id = gtid();
    if (id >= R_N * IO) return;
    int r = id / IO, io = id % IO;
    float acc = 0.f;
#pragma unroll
    for (int b = 0; b < 32; ++b) acc = fmaf(att[r * 32 + b], basis[b * IO + io], acc);
    W[id] = acc;
}

// per-edge msg = x[src] @ W[rel], stored at dst-sorted slot pos[e] (NO atomics)
template<int IN, int OUT>
__global__ __launch_bounds__(256) void k_rgcn_msg(const float* __restrict__ x,
                                                  const int* __restrict__ src,
                                                  const int* __restrict__ pos,
                                                  const float* __restrict__ Wall,
                                                  float* __restrict__ msg) {
    constexpr int CPT = 4;
    constexpr int GP  = OUT / CPT;
    constexpr int EPI = 256 / GP;
    constexpr int EB  = 2 * EPI;
    __shared__ float ws[IN * OUT];
    int tid = threadIdx.x;
    int e0 = blockIdx.x * EB;
    int rel = e0 >> 14;               // /EPER; EB divides EPER
    for (int i = tid; i < IN * OUT; i += 256) ws[i] = Wall[rel * IN * OUT + i];
    __syncthreads();
    int c0 = (tid % GP) * CPT;
    int el = tid / GP;
    int ea = e0 + el, eb = e0 + EPI + el;
    int sa = src[ea], sb = src[eb];
    const float4* xa = (const float4*)(x + (size_t)sa * IN);
    const float4* xb = (const float4*)(x + (size_t)sb * IN);
    float acca[4] = {0.f, 0.f, 0.f, 0.f};
    float accb[4] = {0.f, 0.f, 0.f, 0.f};
#pragma unroll
    for (int k4 = 0; k4 < IN / 4; ++k4) {
        float4 va = xa[k4], vb = xb[k4];
#pragma unroll
        for (int kk = 0; kk < 4; ++kk) {
            int k = k4 * 4 + kk;
            float4 w = *(const float4*)&ws[k * OUT + c0];
            float fa = kk == 0 ? va.x : kk == 1 ? va.y : kk == 2 ? va.z : va.w;
            float fb = kk == 0 ? vb.x : kk == 1 ? vb.y : kk == 2 ? vb.z : vb.w;
            acca[0] = fmaf(fa, w.x, acca[0]); acca[1] = fmaf(fa, w.y, acca[1]);
            acca[2] = fmaf(fa, w.z, acca[2]); acca[3] = fmaf(fa, w.w, acca[3]);
            accb[0] = fmaf(fb, w.x, accb[0]); accb[1] = fmaf(fb, w.y, accb[1]);
            accb[2] = fmaf(fb, w.z, accb[2]); accb[3] = fmaf(fb, w.w, accb[3]);
        }
    }
    int pa = pos[ea], pb = pos[eb];
    *(float4*)&msg[(size_t)pa * OUT + c0] = make_float4(acca[0], acca[1], acca[2], acca[3]);
    *(float4*)&msg[(size_t)pb * OUT + c0] = make_float4(accb[0], accb[1], accb[2], accb[3]);
}

// out[d] = mean(msg segment) + x[d] @ root (+relu); msg is dst-sorted -> streaming reads
template<int IN, int OUT>
__global__ __launch_bounds__(256) void k_rgcn_gather(const float* __restrict__ msg,
                                                     const int* __restrict__ start, const int* __restrict__ cnt,
                                                     const float* __restrict__ x, const float* __restrict__ root,
                                                     float* __restrict__ out, int relu) {
    int g = blockIdx.x * (256 / OUT) + threadIdx.x / OUT;
    int c = threadIdx.x % OUT;
    if (g >= D_N) return;
    int s0 = start[g], n = cnt[g];
    float acc = 0.f;
    for (int i = s0; i < s0 + n; ++i) acc += msg[(size_t)i * OUT + c];
    acc /= fmaxf((float)n, 1.f);
#pragma unroll
    for (int k = 0; k < IN; ++k) acc = fmaf(x[(size_t)g * IN + k], root[k * OUT + c], acc);
    out[(size_t)g * OUT + c] = relu ? fmaxf(acc, 0.f) : acc;
}

extern "C" void kernel_launch(void* const* d_in, const int* in_sizes, int n_in,
                              void* d_out, int out_size, void* d_ws, size_t ws_size,
                              hipStream_t stream) {
    const float* x_drug   = (const float*)d_in[0];
    const int*   dd_ei    = (const int*)d_in[1];
    const float* d_norm   = (const float*)d_in[4];
    const float* x_prot   = (const float*)d_in[5];
    const int*   pp_ei    = (const int*)d_in[6];
    const int*   dp_ei    = (const int*)d_in[7];
    const float* gcn_w1   = (const float*)d_in[9];
    const float* gcn_b1   = (const float*)d_in[10];
    const float* gcn_w2   = (const float*)d_in[11];
    const float* gcn_b2   = (const float*)d_in[12];
    const float* embed    = (const float*)d_in[13];
    const float* hgcn_w   = (const float*)d_in[14];
    const float* r1_basis = (const float*)d_in[15];
    const float* r1_att   = (const float*)d_in[16];
    const float* r1_root  = (const float*)d_in[17];
    const float* r2_basis = (const float*)d_in[18];
    const float* r2_att   = (const float*)d_in[19];
    const float* r2_root  = (const float*)d_in[20];
    float* out = (float*)d_out;

    char* ws = (char*)d_ws;
    size_t off = 0;
    auto alloci = [&](size_t n) { int* p = (int*)(ws + off); off += ((n * 4 + 255) & ~(size_t)255); return p; };
    auto allocf = [&](size_t n) { float* p = (float*)(ws + off); off += ((n * 4 + 255) & ~(size_t)255); return p; };
    // ---- zeroed region: the three histograms ----
    int* pp_cnt = alloci(P_N);
    int* dd_cnt = alloci(D_N);
    int* dp_cnt = alloci(D_N);
    size_t zbytes = off;
    // ---- scratch (written before read) ----
    int* pp_start = alloci(P_N);  int* pp_cur = alloci(P_N);  int* pp_srcs = alloci(EPP_N);
    int* dd_start = alloci(D_N);  int* dd_cur = alloci(D_N);  int* dd_pos  = alloci(EDD_N);
    int* dp_start = alloci(D_N);  int* dp_cur = alloci(D_N);  int* dp_srcs = alloci(EDP_N);
    float* dinv = allocf(P_N);
    float* h1   = allocf((size_t)P_N * GH1_N);
    float* agg1 = allocf((size_t)P_N * GH1_N);
    float* h2   = allocf((size_t)P_N * GH2_N);
    float* agg2 = allocf((size_t)P_N * GH2_N);
    float* xcat = allocf((size_t)D_N * IN1_N);
    float* W1   = allocf((size_t)R_N * IN1_N * NH1_N);
    float* W2   = allocf((size_t)R_N * NH1_N * NH2_N);
    float* h1d  = allocf((size_t)D_N * NH1_N);
    float* pbuf = allocf((size_t)EMB_KS * D_N * 48);   // embed partials (15.4 MB)
    float* msg  = allocf((size_t)EDD_N * NH1_N);       // 134 MB; reused by layer 2

    hipMemsetAsync(d_ws, 0, zbytes, stream);

    auto g = [](int n) { return (n + 255) / 256; };
    const int *pp_src = pp_ei, *pp_dst = pp_ei + EPP_N;
    const int *dd_src = dd_ei, *dd_dst = dd_ei + EDD_N;
    const int *dp_src = dp_ei, *dp_dst = dp_ei + EDP_N;

    // ---- CSR builds (int atomics only) ----
    k_hist<<<g(EPP_N), 256, 0, stream>>>(pp_dst, EPP_N, 0, pp_cnt);
    k_hist<<<g(EDD_N), 256, 0, stream>>>(dd_dst, EDD_N, 0, dd_cnt);
    k_hist<<<g(EDP_N), 256, 0, stream>>>(dp_dst, EDP_N, P_N, dp_cnt);
    k_scan<<<1, 1024, 0, stream>>>(pp_cnt, P_N, pp_start, pp_cur);
    k_scan<<<1, 1024, 0, stream>>>(dd_cnt, D_N, dd_start, dd_cur);
    k_scan<<<1, 1024, 0, stream>>>(dp_cnt, D_N, dp_start, dp_cur);
    k_permute_src<<<g(EPP_N), 256, 0, stream>>>(pp_src, pp_dst, EPP_N, 0, pp_cur, pp_srcs);
    k_rank<<<g(EDD_N), 256, 0, stream>>>(dd_dst, EDD_N, 0, dd_cur, dd_pos);
    k_permute_src<<<g(EDP_N), 256, 0, stream>>>(dp_src, dp_dst, EDP_N, P_N, dp_cur, dp_srcs);

    // ---- PPEncoder (gather form) ----
    k_dinv<<<g(P_N), 256, 0, stream>>>(pp_cnt, dinv, P_N);
    k_matmul<128, GH1_N><<<g(P_N * GH1_N), 256, 0, stream>>>(x_prot, gcn_w1, h1, P_N);
    k_gcn_gather<GH1_N><<<(P_N + 7) / 8, 256, 0, stream>>>(h1, dinv, pp_srcs, pp_start, pp_cnt, gcn_b1, agg1, P_N, 1);
    k_matmul<GH1_N, GH2_N><<<g(P_N * GH2_N), 256, 0, stream>>>(agg1, gcn_w2, h2, P_N);
    k_gcn_gather<GH2_N><<<(P_N + 15) / 16, 256, 0, stream>>>(h2, dinv, pp_srcs, pp_start, pp_cnt, gcn_b2, agg2, P_N, 0);

    // ---- hierarchy conv + drug embedding -> xcat ----
    k_dp_gather<<<(D_N + 15) / 16, 256, 0, stream>>>(agg2, dp_srcs, dp_start, dp_cnt, hgcn_w, xcat);
    k_embed_part<<<dim3((D_N + EMB_BR - 1) / EMB_BR, EMB_KS), 192, 0, stream>>>(x_drug, embed, pbuf);
    k_embed_reduce<<<g(D_N * 48), 256, 0, stream>>>(pbuf, d_norm, xcat);

    // ---- RGCN weights ----
    k_rgcn_w<<<g(R_N * IN1_N * NH1_N), 256, 0, stream>>>(r1_att, r1_basis, W1, IN1_N * NH1_N);
    k_rgcn_w<<<g(R_N * NH1_N * NH2_N), 256, 0, stream>>>(r2_att, r2_basis, W2, NH1_N * NH2_N);

    // ---- RGCN layer 1 (relu) ----
    k_rgcn_msg<IN1_N, NH1_N><<<EDD_N / 64, 256, 0, stream>>>(xcat, dd_src, dd_pos, W1, msg);
    k_rgcn_gather<IN1_N, NH1_N><<<(D_N + 7) / 8, 256, 0, stream>>>(msg, dd_start, dd_cnt, xcat, r1_root, h1d, 1);
    // ---- RGCN layer 2 (final) ----
    k_rgcn_msg<NH1_N, NH2_N><<<EDD_N / 128, 256, 0, stream>>>(h1d, dd_src, dd_pos, W2, msg);
    k_rgcn_gather<NH1_N, NH2_N><<<(D_N + 15) / 16, 256, 0, stream>>>(msg, dd_start, dd_cnt, h1d, r2_root, out, 0);
}

// Round 11
// 750.978 us; speedup vs baseline: 1.8025x; 1.0093x over previous
//
#include <hip/hip_runtime.h>

#define P_N    20000
#define D_N    10000
#define R_N    64
#define EPER_N 16384
#define EDD_N  (R_N*EPER_N)
#define EPP_N  640000
#define EDP_N  160000
#define NE_N   48
#define PD_N   16
#define IN1_N  64   // NE+PD
#define NH1_N  32
#define NH2_N  16
#define GH1_N  32
#define GH2_N  16
#define EMB_KS 8            // K-splits for the embed GEMM
#define EMB_KC (2048/EMB_KS)
#define EMB_BR 64           // rows per block

static __device__ __forceinline__ int gtid() { return blockIdx.x * blockDim.x + threadIdx.x; }

// ---------- CSR build ----------
__global__ void k_hist(const int* __restrict__ dst, int E, int off, int* __restrict__ cnt) {
    int i = gtid();
    if (i < E) atomicAdd(&cnt[dst[i] - off], 1);
}

// fused exclusive scans: block 0 -> pp (P_N), block 1 -> dd (D_N), block 2 -> dp (D_N)
__global__ __launch_bounds__(1024) void k_scan3(const int* __restrict__ pp_cnt, int* __restrict__ pp_start, int* __restrict__ pp_cur,
                                                const int* __restrict__ dd_cnt, int* __restrict__ dd_start, int* __restrict__ dd_cur,
                                                const int* __restrict__ dp_cnt, int* __restrict__ dp_start, int* __restrict__ dp_cur) {
    const int* cnt; int* start; int* cursor; int n;
    if (blockIdx.x == 0)      { cnt = pp_cnt; start = pp_start; cursor = pp_cur; n = P_N; }
    else if (blockIdx.x == 1) { cnt = dd_cnt; start = dd_start; cursor = dd_cur; n = D_N; }
    else                      { cnt = dp_cnt; start = dp_start; cursor = dp_cur; n = D_N; }
    __shared__ int wsum[16];
    __shared__ int carrySh, totSh;
    int lane = threadIdx.x & 63, wid = threadIdx.x >> 6;
    if (threadIdx.x == 0) carrySh = 0;
    __syncthreads();
    for (int base = 0; base < n; base += 1024) {
        int i = base + threadIdx.x;
        int v = (i < n) ? cnt[i] : 0;
        int s = v;
#pragma unroll
        for (int ofs = 1; ofs < 64; ofs <<= 1) {
            int t = __shfl_up(s, ofs);
            if (lane >= ofs) s += t;
        }
        if (lane == 63) wsum[wid] = s;
        __syncthreads();
        if (threadIdx.x == 0) {
            int run = 0;
#pragma unroll
            for (int k = 0; k < 16; ++k) { int t = wsum[k]; wsum[k] = run; run += t; }
            totSh = run;
        }
        __syncthreads();
        int excl = carrySh + wsum[wid] + (s - v);
        if (i < n) { start[i] = excl; cursor[i] = excl; }
        __syncthreads();
        if (threadIdx.x == 0) carrySh += totSh;
        __syncthreads();
    }
}

// pos[e] = absolute sorted slot (cursor pre-loaded with start)
__global__ void k_rank(const int* __restrict__ dst, int E, int off,
                       int* __restrict__ cursor, int* __restrict__ pos) {
    int i = gtid();
    if (i < E) pos[i] = atomicAdd(&cursor[dst[i] - off], 1);
}

// srcs[slot] = src[e]  (payload permute for gather-only aggregations)
__global__ void k_permute_src(const int* __restrict__ src, const int* __restrict__ dst, int E, int off,
                              int* __restrict__ cursor, int* __restrict__ srcs) {
    int i = gtid();
    if (i < E) srcs[atomicAdd(&cursor[dst[i] - off], 1)] = src[i];
}

__global__ void k_dinv(const int* __restrict__ cnt, float* __restrict__ dinv, int n) {
    int i = gtid();
    if (i < n) dinv[i] = rsqrtf((float)cnt[i] + 1.0f);
}

// ---------- dense helpers ----------
template<int K, int N>
__global__ void k_matmul(const float* __restrict__ A, const float* __restrict__ W,
                         float* __restrict__ C, int M) {
    int id = gtid();
    if (id >= M * N) return;
    int m = id / N, n = id % N;
    const float* a = A + (size_t)m * K;
    float acc = 0.f;
#pragma unroll
    for (int k = 0; k < K; ++k) acc = fmaf(a[k], W[k * N + n], acc);
    C[id] = acc;
}

// GCN aggregate (gather form): out[d] = dinv[d]*sum_e h[s]*dinv[s] + h[d]*dinv[d]^2 + b (+relu)
template<int N>
__global__ __launch_bounds__(256) void k_gcn_gather(const float* __restrict__ h, const float* __restrict__ dinv,
                                                    const int* __restrict__ srcs, const int* __restrict__ start,
                                                    const int* __restrict__ cnt, const float* __restrict__ b,
                                                    float* __restrict__ out, int M, int relu) {
    int g = blockIdx.x * (256 / N) + threadIdx.x / N;
    int c = threadIdx.x % N;
    if (g >= M) return;
    int s0 = start[g], n = cnt[g];
    float acc = 0.f;
    for (int i = s0; i < s0 + n; ++i) {
        int s = srcs[i];
        acc = fmaf(h[(size_t)s * N + c], dinv[s], acc);
    }
    float di = dinv[g];
    float v = acc * di + h[(size_t)g * N + c] * di * di + b[c];
    out[(size_t)g * N + c] = relu ? fmaxf(v, 0.f) : v;
}

// prot->drug mean + 16x16 projection, fused; writes xcat[:,48:64]
__global__ __launch_bounds__(256) void k_dp_gather(const float* __restrict__ hp, const int* __restrict__ srcs,
                                                   const int* __restrict__ start, const int* __restrict__ cnt,
                                                   const float* __restrict__ w, float* __restrict__ xcat) {
    __shared__ float mean[16][17];
    int lg = threadIdx.x / 16, c = threadIdx.x % 16;
    int d = blockIdx.x * 16 + lg;
    float acc = 0.f;
    int n = 0;
    if (d < D_N) {
        int s0 = start[d]; n = cnt[d];
        for (int i = s0; i < s0 + n; ++i) acc += hp[(size_t)srcs[i] * PD_N + c];
        acc /= fmaxf((float)n, 1.f);
    }
    mean[lg][c] = acc;
    __syncthreads();
    if (d < D_N) {
        float o = 0.f;
#pragma unroll
        for (int k = 0; k < PD_N; ++k) o = fmaf(mean[lg][k], w[k * PD_N + c], o);
        xcat[(size_t)d * IN1_N + NE_N + c] = o;
    }
}

// embed GEMM, K-split, register-blocked 4x4/thread (VALU-bound; see r10)
__global__ __launch_bounds__(192) void k_embed_part(const float* __restrict__ xd,
                                                    const float* __restrict__ emb,
                                                    float* __restrict__ pbuf) {
    __shared__ float xs[EMB_BR][68];
    __shared__ float es[64][48];
    int tid = threadIdx.x;
    int row0 = blockIdx.x * EMB_BR;
    int kbase = blockIdx.y * EMB_KC;
    int colg = tid % 12, rowg = tid / 12;
    float4 acc[4] = {{0,0,0,0},{0,0,0,0},{0,0,0,0},{0,0,0,0}};
    for (int k0 = kbase; k0 < kbase + EMB_KC; k0 += 64) {
        __syncthreads();
        for (int i = tid; i < 768; i += 192)
            ((float4*)es)[i] = ((const float4*)(emb + (size_t)k0 * 48))[i];
        for (int i = tid; i < EMB_BR * 16; i += 192) {
            int rr = i / 16, f4 = i % 16;
            int grow = row0 + rr;
            float4 v = make_float4(0.f, 0.f, 0.f, 0.f);
            if (grow < D_N) v = *(const float4*)&xd[(size_t)grow * 2048 + k0 + 4 * f4];
            *(float4*)&xs[rr][4 * f4] = v;
        }
        __syncthreads();
#pragma unroll 4
        for (int ks = 0; ks < 16; ++ks) {
            float4 x0 = *(float4*)&xs[4 * rowg + 0][4 * ks];
            float4 x1 = *(float4*)&xs[4 * rowg + 1][4 * ks];
            float4 x2 = *(float4*)&xs[4 * rowg + 2][4 * ks];
            float4 x3 = *(float4*)&xs[4 * rowg + 3][4 * ks];
            float4 w0 = *(float4*)&es[4 * ks + 0][4 * colg];
            float4 w1 = *(float4*)&es[4 * ks + 1][4 * colg];
            float4 w2 = *(float4*)&es[4 * ks + 2][4 * colg];
            float4 w3 = *(float4*)&es[4 * ks + 3][4 * colg];
#define EMB_FMA(i, xv) \
            acc[i].x = fmaf(xv.x, w0.x, acc[i].x); acc[i].y = fmaf(xv.x, w0.y, acc[i].y); \
            acc[i].z = fmaf(xv.x, w0.z, acc[i].z); acc[i].w = fmaf(xv.x, w0.w, acc[i].w); \
            acc[i].x = fmaf(xv.y, w1.x, acc[i].x); acc[i].y = fmaf(xv.y, w1.y, acc[i].y); \
            acc[i].z = fmaf(xv.y, w1.z, acc[i].z); acc[i].w = fmaf(xv.y, w1.w, acc[i].w); \
            acc[i].x = fmaf(xv.z, w2.x, acc[i].x); acc[i].y = fmaf(xv.z, w2.y, acc[i].y); \
            acc[i].z = fmaf(xv.z, w2.z, acc[i].z); acc[i].w = fmaf(xv.z, w2.w, acc[i].w); \
            acc[i].x = fmaf(xv.w, w3.x, acc[i].x); acc[i].y = fmaf(xv.w, w3.y, acc[i].y); \
            acc[i].z = fmaf(xv.w, w3.z, acc[i].z); acc[i].w = fmaf(xv.w, w3.w, acc[i].w);
            EMB_FMA(0, x0) EMB_FMA(1, x1) EMB_FMA(2, x2) EMB_FMA(3, x3)
#undef EMB_FMA
        }
    }
#pragma unroll
    for (int i = 0; i < 4; ++i) {
        int grow = row0 + 4 * rowg + i;
        if (grow < D_N)
            *(float4*)&pbuf[((size_t)blockIdx.y * D_N + grow) * 48 + 4 * colg] = acc[i];
    }
}

// xcat[:,0:48] = (sum of EMB_KS partials) / d_norm
__global__ void k_embed_reduce(const float* __restrict__ pbuf, const float* __restrict__ dnorm,
                               float* __restrict__ xcat) {
    int id = gtid();
    if (id >= D_N * 48) return;
    int d = id / 48, c = id % 48;
    float acc = 0.f;
#pragma unroll
    for (int ks = 0; ks < EMB_KS; ++ks) acc += pbuf[((size_t)ks * D_N + d) * 48 + c];
    xcat[(size_t)d * IN1_N + c] = acc / dnorm[d];
}

__global__ void k_rgcn_w(const float* __restrict__ att, const float* __restrict__ basis,
                         float* __restrict__ W, int IO) {
    int id = gtid();
    if (id >= R_N * IO) return;
    int r = id / IO, io = id % IO;
    float acc = 0.f;
#pragma unroll
    for (int b = 0; b < 32; ++b) acc = fmaf(att[r * 32 + b], basis[b * IO + io], acc);
    W[id] = acc;
}

// per-edge msg = x[src] @ W[rel], stored at dst-sorted slot pos[e].
// 4 edges x 4 cols per thread: each ws float4 read serves 4 edges (16 FMA) -> VALU-bound.
template<int IN, int OUT>
__global__ __launch_bounds__(256) void k_rgcn_msg(const float* __restrict__ x,
                                                  const int* __restrict__ src,
                                                  const int* __restrict__ pos,
                                                  const float* __restrict__ Wall,
                                                  float* __restrict__ msg) {
    constexpr int CPT = 4;
    constexpr int GP  = OUT / CPT;          // col groups
    constexpr int EPT = 4;                  // edges per thread
    constexpr int EB  = (256 / GP) * EPT;   // edges per block (128 / 256)
    __shared__ float ws[IN * OUT];
    int tid = threadIdx.x;
    int e0 = blockIdx.x * EB;
    int rel = e0 >> 14;                     // /EPER; EB divides EPER
    for (int i = tid; i < IN * OUT; i += 256) ws[i] = Wall[rel * IN * OUT + i];
    __syncthreads();
    int c0 = (tid % GP) * CPT;
    int eb0 = e0 + (tid / GP) * EPT;
    int s[EPT];
#pragma unroll
    for (int j = 0; j < EPT; ++j) s[j] = src[eb0 + j];
    float4 acc[EPT];
#pragma unroll
    for (int j = 0; j < EPT; ++j) acc[j] = make_float4(0.f, 0.f, 0.f, 0.f);
#pragma unroll
    for (int k4 = 0; k4 < IN / 4; ++k4) {
        float4 xv[EPT];
#pragma unroll
        for (int j = 0; j < EPT; ++j)
            xv[j] = *(const float4*)&x[(size_t)s[j] * IN + 4 * k4];
        float4 w0 = *(const float4*)&ws[(4 * k4 + 0) * OUT + c0];
        float4 w1 = *(const float4*)&ws[(4 * k4 + 1) * OUT + c0];
        float4 w2 = *(const float4*)&ws[(4 * k4 + 2) * OUT + c0];
        float4 w3 = *(const float4*)&ws[(4 * k4 + 3) * OUT + c0];
#pragma unroll
        for (int j = 0; j < EPT; ++j) {
            acc[j].x = fmaf(xv[j].x, w0.x, acc[j].x); acc[j].y = fmaf(xv[j].x, w0.y, acc[j].y);
            acc[j].z = fmaf(xv[j].x, w0.z, acc[j].z); acc[j].w = fmaf(xv[j].x, w0.w, acc[j].w);
            acc[j].x = fmaf(xv[j].y, w1.x, acc[j].x); acc[j].y = fmaf(xv[j].y, w1.y, acc[j].y);
            acc[j].z = fmaf(xv[j].y, w1.z, acc[j].z); acc[j].w = fmaf(xv[j].y, w1.w, acc[j].w);
            acc[j].x = fmaf(xv[j].z, w2.x, acc[j].x); acc[j].y = fmaf(xv[j].z, w2.y, acc[j].y);
            acc[j].z = fmaf(xv[j].z, w2.z, acc[j].z); acc[j].w = fmaf(xv[j].z, w2.w, acc[j].w);
            acc[j].x = fmaf(xv[j].w, w3.x, acc[j].x); acc[j].y = fmaf(xv[j].w, w3.y, acc[j].y);
            acc[j].z = fmaf(xv[j].w, w3.z, acc[j].z); acc[j].w = fmaf(xv[j].w, w3.w, acc[j].w);
        }
    }
#pragma unroll
    for (int j = 0; j < EPT; ++j)
        *(float4*)&msg[(size_t)pos[eb0 + j] * OUT + c0] = acc[j];
}

// out[d] = mean(msg segment) + x[d] @ root (+relu); msg is dst-sorted -> streaming reads
template<int IN, int OUT>
__global__ __launch_bounds__(256) void k_rgcn_gather(const float* __restrict__ msg,
                                                     const int* __restrict__ start, const int* __restrict__ cnt,
                                                     const float* __restrict__ x, const float* __restrict__ root,
                                                     float* __restrict__ out, int relu) {
    int g = blockIdx.x * (256 / OUT) + threadIdx.x / OUT;
    int c = threadIdx.x % OUT;
    if (g >= D_N) return;
    int s0 = start[g], n = cnt[g];
    float acc = 0.f;
    for (int i = s0; i < s0 + n; ++i) acc += msg[(size_t)i * OUT + c];
    acc /= fmaxf((float)n, 1.f);
#pragma unroll
    for (int k = 0; k < IN; ++k) acc = fmaf(x[(size_t)g * IN + k], root[k * OUT + c], acc);
    out[(size_t)g * OUT + c] = relu ? fmaxf(acc, 0.f) : acc;
}

extern "C" void kernel_launch(void* const* d_in, const int* in_sizes, int n_in,
                              void* d_out, int out_size, void* d_ws, size_t ws_size,
                              hipStream_t stream) {
    const float* x_drug   = (const float*)d_in[0];
    const int*   dd_ei    = (const int*)d_in[1];
    const float* d_norm   = (const float*)d_in[4];
    const float* x_prot   = (const float*)d_in[5];
    const int*   pp_ei    = (const int*)d_in[6];
    const int*   dp_ei    = (const int*)d_in[7];
    const float* gcn_w1   = (const float*)d_in[9];
    const float* gcn_b1   = (const float*)d_in[10];
    const float* gcn_w2   = (const float*)d_in[11];
    const float* gcn_b2   = (const float*)d_in[12];
    const float* embed    = (const float*)d_in[13];
    const float* hgcn_w   = (const float*)d_in[14];
    const float* r1_basis = (const float*)d_in[15];
    const float* r1_att   = (const float*)d_in[16];
    const float* r1_root  = (const float*)d_in[17];
    const float* r2_basis = (const float*)d_in[18];
    const float* r2_att   = (const float*)d_in[19];
    const float* r2_root  = (const float*)d_in[20];
    float* out = (float*)d_out;

    char* ws = (char*)d_ws;
    size_t off = 0;
    auto alloci = [&](size_t n) { int* p = (int*)(ws + off); off += ((n * 4 + 255) & ~(size_t)255); return p; };
    auto allocf = [&](size_t n) { float* p = (float*)(ws + off); off += ((n * 4 + 255) & ~(size_t)255); return p; };
    // ---- zeroed region: the three histograms ----
    int* pp_cnt = alloci(P_N);
    int* dd_cnt = alloci(D_N);
    int* dp_cnt = alloci(D_N);
    size_t zbytes = off;
    // ---- scratch (written before read) ----
    int* pp_start = alloci(P_N);  int* pp_cur = alloci(P_N);  int* pp_srcs = alloci(EPP_N);
    int* dd_start = alloci(D_N);  int* dd_cur = alloci(D_N);  int* dd_pos  = alloci(EDD_N);
    int* dp_start = alloci(D_N);  int* dp_cur = alloci(D_N);  int* dp_srcs = alloci(EDP_N);
    float* dinv = allocf(P_N);
    float* h1   = allocf((size_t)P_N * GH1_N);
    float* agg1 = allocf((size_t)P_N * GH1_N);
    float* h2   = allocf((size_t)P_N * GH2_N);
    float* agg2 = allocf((size_t)P_N * GH2_N);
    float* xcat = allocf((size_t)D_N * IN1_N);
    float* W1   = allocf((size_t)R_N * IN1_N * NH1_N);
    float* W2   = allocf((size_t)R_N * NH1_N * NH2_N);
    float* h1d  = allocf((size_t)D_N * NH1_N);
    float* pbuf = allocf((size_t)EMB_KS * D_N * 48);   // embed partials (15.4 MB)
    float* msg  = allocf((size_t)EDD_N * NH1_N);       // 134 MB; reused by layer 2

    hipMemsetAsync(d_ws, 0, zbytes, stream);

    auto g = [](int n) { return (n + 255) / 256; };
    const int *pp_src = pp_ei, *pp_dst = pp_ei + EPP_N;
    const int *dd_src = dd_ei, *dd_dst = dd_ei + EDD_N;
    const int *dp_src = dp_ei, *dp_dst = dp_ei + EDP_N;

    // ---- CSR builds (int atomics only) ----
    k_hist<<<g(EPP_N), 256, 0, stream>>>(pp_dst, EPP_N, 0, pp_cnt);
    k_hist<<<g(EDD_N), 256, 0, stream>>>(dd_dst, EDD_N, 0, dd_cnt);
    k_hist<<<g(EDP_N), 256, 0, stream>>>(dp_dst, EDP_N, P_N, dp_cnt);
    k_scan3<<<3, 1024, 0, stream>>>(pp_cnt, pp_start, pp_cur,
                                    dd_cnt, dd_start, dd_cur,
                                    dp_cnt, dp_start, dp_cur);
    k_permute_src<<<g(EPP_N), 256, 0, stream>>>(pp_src, pp_dst, EPP_N, 0, pp_cur, pp_srcs);
    k_rank<<<g(EDD_N), 256, 0, stream>>>(dd_dst, EDD_N, 0, dd_cur, dd_pos);
    k_permute_src<<<g(EDP_N), 256, 0, stream>>>(dp_src, dp_dst, EDP_N, P_N, dp_cur, dp_srcs);

    // ---- PPEncoder (gather form) ----
    k_dinv<<<g(P_N), 256, 0, stream>>>(pp_cnt, dinv, P_N);
    k_matmul<128, GH1_N><<<g(P_N * GH1_N), 256, 0, stream>>>(x_prot, gcn_w1, h1, P_N);
    k_gcn_gather<GH1_N><<<(P_N + 7) / 8, 256, 0, stream>>>(h1, dinv, pp_srcs, pp_start, pp_cnt, gcn_b1, agg1, P_N, 1);
    k_matmul<GH1_N, GH2_N><<<g(P_N * GH2_N), 256, 0, stream>>>(agg1, gcn_w2, h2, P_N);
    k_gcn_gather<GH2_N><<<(P_N + 15) / 16, 256, 0, stream>>>(h2, dinv, pp_srcs, pp_start, pp_cnt, gcn_b2, agg2, P_N, 0);

    // ---- hierarchy conv + drug embedding -> xcat ----
    k_dp_gather<<<(D_N + 15) / 16, 256, 0, stream>>>(agg2, dp_srcs, dp_start, dp_cnt, hgcn_w, xcat);
    k_embed_part<<<dim3((D_N + EMB_BR - 1) / EMB_BR, EMB_KS), 192, 0, stream>>>(x_drug, embed, pbuf);
    k_embed_reduce<<<g(D_N * 48), 256, 0, stream>>>(pbuf, d_norm, xcat);

    // ---- RGCN weights ----
    k_rgcn_w<<<g(R_N * IN1_N * NH1_N), 256, 0, stream>>>(r1_att, r1_basis, W1, IN1_N * NH1_N);
    k_rgcn_w<<<g(R_N * NH1_N * NH2_N), 256, 0, stream>>>(r2_att, r2_basis, W2, NH1_N * NH2_N);

    // ---- RGCN layer 1 (relu) ----  EB=128 for <64,32>
    k_rgcn_msg<IN1_N, NH1_N><<<EDD_N / 128, 256, 0, stream>>>(xcat, dd_src, dd_pos, W1, msg);
    k_rgcn_gather<IN1_N, NH1_N><<<(D_N + 7) / 8, 256, 0, stream>>>(msg, dd_start, dd_cnt, xcat, r1_root, h1d, 1);
    // ---- RGCN layer 2 (final) ----  EB=256 for <32,16>
    k_rgcn_msg<NH1_N, NH2_N><<<EDD_N / 256, 256, 0, stream>>>(h1d, dd_src, dd_pos, W2, msg);
    k_rgcn_gather<NH1_N, NH2_N><<<(D_N + 15) / 16, 256, 0, stream>>>(msg, dd_start, dd_cnt, h1d, r2_root, out, 0);
}